// Round 6
// baseline (974.607 us; speedup 1.0000x reference)
//
#include <hip/hip_runtime.h>
#include <hip/hip_bf16.h>
#include <math.h>

#define SEQ 2048
#define DKH 64
#define NH 16
#define NEGV -10000.0f
#define LIST_CAP 160

typedef __attribute__((ext_vector_type(8))) short short8;
typedef __attribute__((ext_vector_type(4))) float f32x4;

__device__ __forceinline__ unsigned int f2k(float f) {
  unsigned int u = __float_as_uint(f);
  return (u & 0x80000000u) ? ~u : (u | 0x80000000u);
}
__device__ __forceinline__ float k2f(unsigned int k) {
  unsigned int u = (k & 0x80000000u) ? (k & 0x7FFFFFFFu) : ~k;
  return __uint_as_float(u);
}
__device__ __forceinline__ int lanecnt_lt(unsigned long long m) {
  return __builtin_amdgcn_mbcnt_hi((unsigned int)(m >> 32),
         __builtin_amdgcn_mbcnt_lo((unsigned int)m, 0));
}
__device__ __forceinline__ void split_hl(float x, unsigned short* h, unsigned short* l) {
  unsigned int u = __float_as_uint(x);
  *h = (unsigned short)(u >> 16);
  float hf = __uint_as_float(u & 0xffff0000u);
  *l = (unsigned short)(__float_as_uint(x - hf) >> 16);
}
__device__ __forceinline__ void glds16(const unsigned short* g, unsigned short* l) {
  __builtin_amdgcn_global_load_lds(
      (const __attribute__((address_space(1))) unsigned int*)g,
      (__attribute__((address_space(3))) unsigned int*)l, 16, 0, 0);
}

// ---------------------------------------------------------------------------
// fp32 -> [hi(1024) | lo(1024)] bf16 planes, row-major M x 2048 ushort.
// ---------------------------------------------------------------------------
__global__ __launch_bounds__(256)
void conv_xhl(const float* __restrict__ X, unsigned short* __restrict__ O)
{
  int idx = blockIdx.x * 256 + threadIdx.x;   // one thread per 4 elements
  int m = idx >> 8;
  int c = (idx & 255) * 4;
  float4 v = *(const float4*)(X + (size_t)m * 1024 + c);
  float xs[4] = {v.x, v.y, v.z, v.w};
  ushort4 h, l;
  unsigned short hh[4], ll[4];
#pragma unroll
  for (int q = 0; q < 4; q++) split_hl(xs[q], &hh[q], &ll[q]);
  h.x=hh[0]; h.y=hh[1]; h.z=hh[2]; h.w=hh[3];
  l.x=ll[0]; l.y=ll[1]; l.z=ll[2]; l.w=ll[3];
  *(ushort4*)(O + (size_t)m * 2048 + c) = h;
  *(ushort4*)(O + (size_t)m * 2048 + 1024 + c) = l;
}

// Same for weights (1024 x 1024 fp32 -> 1024 x 2048 hl).
__global__ __launch_bounds__(256)
void conv_whl(const float* __restrict__ W, unsigned short* __restrict__ O)
{
  int idx = blockIdx.x * 256 + threadIdx.x;
  int n = idx >> 8;
  int c = (idx & 255) * 4;
  float4 v = *(const float4*)(W + (size_t)n * 1024 + c);
  float xs[4] = {v.x, v.y, v.z, v.w};
  ushort4 h, l;
  unsigned short hh[4], ll[4];
#pragma unroll
  for (int q = 0; q < 4; q++) split_hl(xs[q], &hh[q], &ll[q]);
  h.x=hh[0]; h.y=hh[1]; h.z=hh[2]; h.w=hh[3];
  l.x=ll[0]; l.y=ll[1]; l.z=ll[2]; l.w=ll[3];
  *(ushort4*)(O + (size_t)n * 2048 + c) = h;
  *(ushort4*)(O + (size_t)n * 2048 + 1024 + c) = l;
}

// ---------------------------------------------------------------------------
// Split-bf16 MFMA GEMM: C[m,n] = sum_c X[m,c]*W[n,c] + bias[n] computed as
// Xhi*Whi + Xhi*Wlo + Xlo*Whi via a single ext-K loop (Kext=3072).
// A: M x 2048 hl, B: N x 2048 hl. Tile 128(M) x 64(N), BK=64, 256 thr.
// Epilogue modes: 0 fp32 [m][n]; 1 bhsd hl (q,k); 2 bhsd fp32 (v).
// ---------------------------------------------------------------------------
__global__ __launch_bounds__(256)
void gemm_mfma(const unsigned short* __restrict__ A,
               const unsigned short* __restrict__ Bw,
               const float* __restrict__ bias,
               float* __restrict__ outF,
               unsigned short* __restrict__ outHL,
               float* __restrict__ outBH,
               int mode)
{
  __shared__ unsigned short As[128 * 64];
  __shared__ unsigned short Bs[64 * 64];
  const int t = threadIdx.x, lane = t & 63, w = t >> 6;
  const int nb = blockIdx.x & 15, mb = blockIdx.x >> 4;
  const int m0 = mb * 128, n0 = nb * 64;
  const int am = lane & 15, aq = lane >> 4;
  const int wr = w >> 1, wc = w & 1;
  const int srow = lane >> 3;
  const int scol = (lane & 7) * 8;

  f32x4 acc[4][2];
#pragma unroll
  for (int mt = 0; mt < 4; mt++)
#pragma unroll
    for (int nt = 0; nt < 2; nt++) acc[mt][nt] = (f32x4){0.f, 0.f, 0.f, 0.f};

  for (int kx = 0; kx < 3072; kx += 64) {
    const int acol = (kx < 1024) ? kx : kx - 1024;   // hi, hi, lo
    const int bcol = (kx < 2048) ? kx : kx - 2048;   // hi, lo, hi
    __syncthreads();
#pragma unroll
    for (int ch = 0; ch < 4; ch++) {                 // A: 128 rows, 4 chunks/wave
      int row = w * 32 + ch * 8 + srow;
      glds16(A + (size_t)(m0 + row) * 2048 + acol + scol,
             &As[(w * 32 + ch * 8) * 64 + lane * 8]);
    }
#pragma unroll
    for (int ch = 0; ch < 2; ch++) {                 // B: 64 rows, 2 chunks/wave
      int row = w * 16 + ch * 8 + srow;
      glds16(Bw + (size_t)(n0 + row) * 2048 + bcol + scol,
             &Bs[(w * 16 + ch * 8) * 64 + lane * 8]);
    }
    __syncthreads();

    short8 af[4][2], bf[2][2];
#pragma unroll
    for (int kk = 0; kk < 2; kk++) {
#pragma unroll
      for (int mt = 0; mt < 4; mt++)
        af[mt][kk] = *(const short8*)&As[(wr * 64 + mt * 16 + am) * 64 + kk * 32 + aq * 8];
#pragma unroll
      for (int nt = 0; nt < 2; nt++)
        bf[nt][kk] = *(const short8*)&Bs[(wc * 32 + nt * 16 + am) * 64 + kk * 32 + aq * 8];
    }
#pragma unroll
    for (int kk = 0; kk < 2; kk++)
#pragma unroll
      for (int mt = 0; mt < 4; mt++)
#pragma unroll
        for (int nt = 0; nt < 2; nt++)
          acc[mt][nt] = __builtin_amdgcn_mfma_f32_16x16x32_bf16(af[mt][kk], bf[nt][kk], acc[mt][nt], 0, 0, 0);
  }

#pragma unroll
  for (int mt = 0; mt < 4; mt++)
#pragma unroll
    for (int nt = 0; nt < 2; nt++)
#pragma unroll
      for (int reg = 0; reg < 4; reg++) {
        const int gm = m0 + wr * 64 + mt * 16 + aq * 4 + reg;
        const int gn = n0 + wc * 32 + nt * 16 + am;
        float val = acc[mt][nt][reg] + bias[gn];
        if (mode == 0) {
          outF[(size_t)gm * 1024 + gn] = val;
        } else {
          const int bb = gm >> 11, s = gm & 2047, h2 = gn >> 6, d = gn & 63;
          const size_t row = ((size_t)(bb * NH + h2)) * SEQ + s;
          if (mode == 2) {
            outBH[row * DKH + d] = val;
          } else {
            unsigned short h, l;
            split_hl(val, &h, &l);
            outHL[row * 128 + d] = h;
            outHL[row * 128 + 64 + d] = l;
          }
        }
      }
}

// ---------------------------------------------------------------------------
// Attention: split-bf16 MFMA QK^T + exact causal top-64 + sparse PV.
// Occupancy-focused: NO monolithic score buffer. Phase 1 streams 256-col
// chunks through a 2x8KB double-buffered LDS stage; wave w absorbs its row
// into register-resident keys[32] right after each chunk (1 sync/chunk).
// LDS ~29KB -> 3 blocks/CU (was 2 at 78KB).
// ---------------------------------------------------------------------------
struct AttnSmem {
  float stage[2][8][256];               // 16 KB double-buffered chunk stage
  float2 pl[8][LIST_CAP + 8];           // packed (p, j) kept list + zero pad
  float cand[8][64];
};

__global__ __launch_bounds__(512, 6)
void attn_topk(const unsigned short* __restrict__ qhl, const unsigned short* __restrict__ khl,
               const float* __restrict__ vp, unsigned short* __restrict__ aohl)
{
  __shared__ AttnSmem sm;
  const int t    = threadIdx.x;
  const int lane = t & 63;
  const int w    = t >> 6;            // 0..7
  const int bh   = blockIdx.x >> 8;
  const int rb   = 255 - (blockIdx.x & 255);   // heavy blocks dispatch first
  const int i0   = rb * 8;
  const unsigned short* qb = qhl + (size_t)bh * SEQ * 128;
  const unsigned short* kb = khl + (size_t)bh * SEQ * 128;
  const float* vbase = vp + (size_t)bh * SEQ * DKH;

  const int am   = lane & 15;
  const int aq   = lane >> 4;
  const int dofs = aq * 8;

  // A-frags: q rows i0..i0+15 (rows 8..15 over-read -> lands in next buffer)
  short8 a_hi[2], a_lo[2];
#pragma unroll
  for (int c = 0; c < 2; c++) {
    size_t off = (size_t)(i0 + am) * 128 + c * 32 + dofs;
    a_hi[c] = *(const short8*)(qb + off);
    a_lo[c] = *(const short8*)(qb + off + 64);
  }

  const int r = w;
  const int i = i0 + w;

  unsigned int keys[32];
#pragma unroll
  for (int u = 0; u < 32; u++) keys[u] = f2k(NEGV);
  float vmax = NEGV, s1 = 0.0f, s2 = 0.0f;

  // ---- phase 1: chunked MFMA QK^T -> stage -> keys (fused stats) ----
  const int cmax = i0 >> 8;
  for (int ch = 0; ch <= cmax; ch++) {
    const int buf = ch & 1;
    for (int e = 0; e < 2; e++) {
      const int j0 = ch * 256 + (2 * w + e) * 16;
      f32x4 C = {0.0f, 0.0f, 0.0f, 0.0f};
      if (j0 <= i0 + 7) {
        short8 b_hi[2], b_lo[2];
#pragma unroll
        for (int c = 0; c < 2; c++) {
          size_t off = (size_t)(j0 + am) * 128 + c * 32 + dofs;
          b_hi[c] = *(const short8*)(kb + off);
          b_lo[c] = *(const short8*)(kb + off + 64);
        }
#pragma unroll
        for (int c = 0; c < 2; c++) {
          C = __builtin_amdgcn_mfma_f32_16x16x32_bf16(a_hi[c], b_hi[c], C, 0, 0, 0);
          C = __builtin_amdgcn_mfma_f32_16x16x32_bf16(a_lo[c], b_hi[c], C, 0, 0, 0);
          C = __builtin_amdgcn_mfma_f32_16x16x32_bf16(a_hi[c], b_lo[c], C, 0, 0, 0);
        }
      }
      if (aq < 2) {
        const int jc = (2 * w + e) * 16 + am;     // col within chunk
        const int j  = ch * 256 + jc;
        const bool live = (j0 <= i0 + 7);
#pragma unroll
        for (int reg = 0; reg < 4; reg++) {
          const int rr = aq * 4 + reg;
          sm.stage[buf][rr][jc] = (live && j <= i0 + rr) ? C[reg] * 0.125f : NEGV;
        }
      }
    }
    __syncthreads();
    // absorb row w's chunk into keys + stats (per-row causal NEG already set)
#pragma unroll
    for (int q = 0; q < 4; q++) {
      float v = sm.stage[buf][r][q * 64 + lane];
      vmax = fmaxf(vmax, v);
      float va = (v > -5000.0f) ? v : 0.0f;
      s1 += va;
      s2 = fmaf(va, va, s2);
      keys[ch * 4 + q] = f2k(v);
    }
  }
#pragma unroll
  for (int off = 32; off; off >>= 1) {
    vmax = fmaxf(vmax, __shfl_xor(vmax, off));
    s1 += __shfl_xor(s1, off);
    s2 += __shfl_xor(s2, off);
  }

  // ---- phase 2: exact top-64 threshold ----
  const int bb = bh >> 4, hh = bh & 15;

  auto countge = [&](unsigned int km) -> int {
    int cnt = 0;
#pragma unroll
    for (int u = 0; u < 32; u++)
      if ((u << 6) <= i)
        cnt += __popcll(__ballot(keys[u] >= km));
    return cnt;
  };

  float vk;
  if (i + 1 <= 64) {
    vk = NEGV;                         // <=64 valid: keep all
  } else {
    const float n1  = (float)(i + 1);
    const float mu  = s1 / n1;
    const float sig = sqrtf(fmaxf(s2 / n1 - mu * mu, 0.0f));
    // inverse-normal probe targeting count ~128 (Hastings approx)
    const float qf = fminf(0.45f, 128.0f / n1);
    const float tq = sqrtf(-2.0f * __logf(qf));
    const float zq = tq - (2.30753f + 0.27061f * tq) /
                          (1.0f + tq * (0.99229f + 0.04481f * tq));
    unsigned int ka, kb2;
    int ca, cb;
    {
      const float t1 = mu + zq * sig;
      const unsigned int kt1 = f2k(t1);
      const int c1 = countge(kt1);
      if (c1 >= 64) { ka = kt1; ca = c1; kb2 = f2k(vmax) + 1u; cb = 0; }
      else {
        const float t2 = mu + (zq - 0.85f) * sig;
        const unsigned int kt2 = f2k(t2);
        const int c2 = countge(kt2);
        if (c2 >= 64) { ka = kt2; ca = c2; kb2 = kt1; cb = c1; }
        else { ka = f2k(-5000.0f); ca = i + 1; kb2 = kt2; cb = c2; }
      }
    }
    int guard = 0;
    while (kb2 - ka > 1u && (ca - cb) > 56 && guard < 64) {
      guard++;
      float fm = 0.5f * (k2f(ka) + k2f(kb2));
      unsigned int km = f2k(fm);
      if (km <= ka || km >= kb2) km = ka + ((kb2 - ka) >> 1);
      const int cnt = countge(km);
      if (cnt >= 64) { ka = km; ca = cnt; } else { kb2 = km; cb = cnt; }
    }
    if (kb2 - ka == 1u || (ca - cb) > 64) {
      vk = k2f(ka);                    // interval collapsed (dups) -> exact
    } else {
      int cbase = 0;
#pragma unroll
      for (int u = 0; u < 32; u++) {
        if ((u << 6) <= i) {
          unsigned int kx = keys[u];
          bool in = (kx >= ka && kx < kb2);
          unsigned long long mask = __ballot(in);
          if (in) sm.cand[w][cbase + lanecnt_lt(mask)] = k2f(kx);
          cbase += __popcll(mask);
        }
      }
      const int nc = cbase;            // <= 64 on this path
      float cv = (lane < nc) ? sm.cand[w][lane] : -3.4e38f;
      for (int ks = 2; ks <= 64; ks <<= 1) {
        for (int j2 = ks >> 1; j2 > 0; j2 >>= 1) {
          float other = __shfl_xor(cv, j2);
          bool up    = ((lane & ks) == 0);
          bool lower = ((lane & j2) == 0);
          float mn = fminf(cv, other), mx = fmaxf(cv, other);
          cv = (up == lower) ? mn : mx;
        }
      }
      int need = 64 - cb;
      vk = __shfl(cv, 64 - need);
    }
  }

  // softmax + packed (p, j) kept list
  float z = 0.0f;
  int base = 0;
#pragma unroll
  for (int u = 0; u < 32; u++) {
    if ((u << 6) <= i) {
      const int j = (u << 6) + lane;
      float sv = k2f(keys[u]);
      float p = (sv >= vk) ? __expf(sv - vmax) : 0.0f;  // NEG entries -> exactly 0
      z += p;
      unsigned long long mask = __ballot(p > 0.0f);
      if (p > 0.0f) {
        int pos = base + lanecnt_lt(mask);
        if (pos < LIST_CAP) {
          float2 e; e.x = p; e.y = __uint_as_float((unsigned int)j);
          sm.pl[r][pos] = e;
        }
      }
      base += __popcll(mask);
    }
  }
#pragma unroll
  for (int off = 32; off; off >>= 1) z += __shfl_xor(z, off);
  const float rz = 1.0f / z;

  // sparse PV: double-buffered batches of 8 (list prefetch + 8 gathers in flight)
  float acc = 0.0f;
  if (base <= LIST_CAP) {
    if (lane < 8) {                    // zero-pad so batches are branch-free
      float2 e; e.x = 0.0f; e.y = __uint_as_float(0u);
      sm.pl[r][base + lane] = e;
    }
    const int nb2 = (base + 7) >> 3;
    float2 cur[8], nxt[8];
#pragma unroll
    for (int s = 0; s < 8; s++) cur[s] = sm.pl[r][s];
    for (int b = 0; b < nb2; b++) {
      float vv[8];
#pragma unroll
      for (int s = 0; s < 8; s++) {
        const unsigned int jx = __float_as_uint(cur[s].y);
        vv[s] = vbase[(size_t)jx * DKH + lane];
      }
      const int nbase = (b + 1) * 8;
#pragma unroll
      for (int s = 0; s < 8; s++) {
        int idx = nbase + s; if (idx > LIST_CAP + 7) idx = 0;
        nxt[s] = sm.pl[r][idx];
      }
#pragma unroll
      for (int s = 0; s < 8; s++) acc = fmaf(cur[s].x, vv[s], acc);
#pragma unroll
      for (int s = 0; s < 8; s++) cur[s] = nxt[s];
    }
  } else {
    // ties pathology: dense PV reconstructed from register keys (broadcast)
    for (int u = 0; u < 32; u++) {
      if ((u << 6) <= i) {
        float sv_l = k2f(keys[u]);
        for (int l2 = 0; l2 < 64; l2++) {
          float sv = __shfl(sv_l, l2);
          const int jx = (u << 6) + l2;
          if (jx <= i) {
            float p = (sv >= vk) ? __expf(sv - vmax) : 0.0f;
            acc = fmaf(p, vbase[(size_t)jx * DKH + lane], acc);
          }
        }
      }
    }
  }

  // epilogue: write ao as hl planes (row-major M x 2048) for the final GEMM
  float val = acc * rz;
  unsigned short h, l;
  split_hl(val, &h, &l);
  const size_t arow = (size_t)(bb * SEQ + i) * 2048;
  aohl[arow + hh * 64 + lane] = h;
  aohl[arow + 1024 + hh * 64 + lane] = l;
}

// ---------------------------------------------------------------------------
extern "C" void kernel_launch(void* const* d_in, const int* in_sizes, int n_in,
                              void* d_out, int out_size, void* d_ws, size_t ws_size,
                              hipStream_t stream)
{
  const float* query = (const float*)d_in[0];
  const float* key   = (const float*)d_in[1];
  const float* value = (const float*)d_in[2];
  const float* Wq    = (const float*)d_in[3];
  const float* bq    = (const float*)d_in[4];
  const float* Wk    = (const float*)d_in[5];
  const float* bk    = (const float*)d_in[6];
  const float* Wv    = (const float*)d_in[7];
  const float* bv    = (const float*)d_in[8];
  const float* Wo    = (const float*)d_in[9];
  const float* bo    = (const float*)d_in[10];

  // ws (52 MB): xhl(16) | qhl(16) | khl(16) | whl(4).
  // Order matters: attn's 16-row MFMA frag over-reads on qhl/khl land in the
  // NEXT buffer (khl / whl) instead of past the workspace end.
  unsigned short* xhl = (unsigned short*)d_ws;            // 4096 x 2048
  unsigned short* qhl = xhl + (size_t)4096 * 2048;        // 65536 x 128 (bhsd hl)
  unsigned short* khl = qhl + (size_t)65536 * 128;
  unsigned short* whl = khl + (size_t)65536 * 128;        // 1024 x 2048
  float* vpf = (float*)d_out;                             // 65536 x 64 fp32 (bhsd)

  hipLaunchKernelGGL(conv_xhl, dim3(4096), dim3(256), 0, stream, query, xhl);
  hipLaunchKernelGGL(conv_whl, dim3(1024), dim3(256), 0, stream, Wq, whl);
  hipLaunchKernelGGL(gemm_mfma, dim3(512), dim3(256), 0, stream, xhl, whl, bq,
                     (float*)nullptr, qhl, (float*)nullptr, 1);
  hipLaunchKernelGGL(conv_xhl, dim3(4096), dim3(256), 0, stream, key, xhl);
  hipLaunchKernelGGL(conv_whl, dim3(1024), dim3(256), 0, stream, Wk, whl);
  hipLaunchKernelGGL(gemm_mfma, dim3(512), dim3(256), 0, stream, xhl, whl, bk,
                     (float*)nullptr, khl, (float*)nullptr, 1);
  hipLaunchKernelGGL(conv_xhl, dim3(4096), dim3(256), 0, stream, value, xhl);
  hipLaunchKernelGGL(conv_whl, dim3(1024), dim3(256), 0, stream, Wv, whl);
  hipLaunchKernelGGL(gemm_mfma, dim3(512), dim3(256), 0, stream, xhl, whl, bv,
                     (float*)nullptr, (unsigned short*)nullptr, vpf, 2);
  hipLaunchKernelGGL(attn_topk, dim3(8192), dim3(512), 0, stream, qhl, khl, vpf, xhl);
  hipLaunchKernelGGL(conv_whl, dim3(1024), dim3(256), 0, stream, Wo, whl);
  hipLaunchKernelGGL(gemm_mfma, dim3(512), dim3(256), 0, stream, xhl, whl, bo,
                     (float*)d_out, (unsigned short*)nullptr, (float*)nullptr, 0);
}